// Round 18
// baseline (213.983 us; speedup 1.0000x reference)
//
#include <hip/hip_runtime.h>
#include <hip/hip_bf16.h>
#include <math.h>

// ---------------- problem constants ----------------
#define NB 32
#define QL 32
#define DL 1024
#define EMB 300
#define EMBP 320            // padded K-dim per tap (zeros 300..319)
#define OD 128
#define KNUM 21
#define VOCAB 50000

typedef short short8 __attribute__((ext_vector_type(8)));
typedef float floatx4 __attribute__((ext_vector_type(4)));
typedef float floatx2 __attribute__((ext_vector_type(2)));

// workspace layout (in float units)
static const size_t WP_OFF  = 0;           // packed bf16 weights: 245760 ushorts = 122880 fl
static const size_t DPK_OFF = 122880;      // packed doc bf16 [32*1024][320] = 5242880 fl
static const size_t QPK_OFF = 5365760;     // packed query bf16 [(1024+2)][320] = 164160 fl
// encoder outputs stored as SPLIT bf16 hi/lo planes
static const size_t QH_OFF  = 5529920;     // qenc hi: 3 * 32*32*128 us = 196608 fl
static const size_t QLO_OFF = 5726528;     // qenc lo
static const size_t DH_OFF  = 5923136;     // denc hi: 3 * 32*1024*128 us = 6291456 fl
static const size_t DLO_OFF = 12214592;    // denc lo
static const size_t ACC_OFF = 18506048;
static const int ACC_SZ = 9 * NB * QL * KNUM;          // 193536

#define QPLANE 131072      // ushorts per z-plane of qenc (32*32*128)
#define DPLANE 4194304     // ushorts per z-plane of denc (32*1024*128)

// combined packed rows: doc (32768) + query (1024) + 2 zero guard rows
#define MROWS (NB * DL + NB * QL)      // 33792 = 264 * 128 exactly
#define MTILES 264
#define CONV_BLOCKS (MTILES * 3)       // 792, divisible by 8 (XCD swizzle bijective)

#define PREPW_N 245760
#define GATHER_N ((MROWS + 2) * 40)
#define ACCZ_N (ACC_SZ / 4)            // 48384 float4 zero-stores

__device__ __constant__ int WPOFF_C[3] = {0, 40960, 122880};

__device__ __forceinline__ void gl_lds16(const ushort* g, char* l) {
    __builtin_amdgcn_global_load_lds(
        (const __attribute__((address_space(1))) unsigned int*)(g),
        (__attribute__((address_space(3))) unsigned int*)(l), 16, 0, 0);
}

__device__ __forceinline__ ushort bf16_bits(float f) {
    __hip_bfloat16 h = __float2bfloat16(f);
    return *reinterpret_cast<ushort*>(&h);
}

// ---------------- fused producer: weights pack + token gather + accb zero ----------------
__global__ void gather_prep(const float* __restrict__ emb,
                            const int* __restrict__ dids, const int* __restrict__ qids,
                            const float* __restrict__ w1, const float* __restrict__ w2,
                            const float* __restrict__ w3,
                            ushort* __restrict__ dpk, ushort* __restrict__ qpk,
                            ushort* __restrict__ wp, float* __restrict__ accb) {
    int idx = blockIdx.x * 256 + threadIdx.x;
    if (idx < PREPW_N) {
        // ---- weights -> bf16, layout [o][j*320+c] ----
        const float* src;
        int k, rel, base;
        if (idx < 40960)        { k = 1; rel = idx;          src = w1; base = 0; }
        else if (idx < 122880)  { k = 2; rel = idx - 40960;  src = w2; base = 40960; }
        else                    { k = 3; rel = idx - 122880; src = w3; base = 122880; }
        int kd = 320 * k;
        int o = rel / kd;
        int jc = rel - o * kd;
        int j = jc / EMBP;
        int c = jc - j * EMBP;
        float f = (c < EMB) ? src[(o * EMB + c) * k + j] : 0.f;
        wp[base + rel] = bf16_bits(f);
        return;
    }
    idx -= PREPW_N;
    if (idx < GATHER_N) {
        // ---- gather token rows: fp32 emb -> packed bf16 [row][320] ----
        const int DROWS = NB * DL;
        int r = idx / 40;
        int c0 = (idx - r * 40) * 8;
        int rid;
        ushort* dst;
        if (r < DROWS) { rid = dids[r]; dst = dpk + (size_t)r * EMBP; }
        else if (r < DROWS + NB * QL) { rid = qids[r - DROWS]; dst = qpk + (size_t)(r - DROWS) * EMBP; }
        else {
            uint4 zz = {0u, 0u, 0u, 0u};
            *reinterpret_cast<uint4*>(qpk + (size_t)(r - DROWS) * EMBP + c0) = zz;
            return;
        }
        const float* erow = emb + (size_t)rid * EMB;
        ushort v[8];
        if (c0 + 8 <= EMB) {
            float4 f0 = *reinterpret_cast<const float4*>(erow + c0);
            float4 f1 = *reinterpret_cast<const float4*>(erow + c0 + 4);
            float fv[8] = {f0.x, f0.y, f0.z, f0.w, f1.x, f1.y, f1.z, f1.w};
#pragma unroll
            for (int i = 0; i < 8; ++i) v[i] = bf16_bits(fv[i]);
        } else {
#pragma unroll
            for (int i = 0; i < 8; ++i) {
                int c = c0 + i;
                v[i] = bf16_bits((c < EMB) ? erow[c] : 0.f);
            }
        }
        *reinterpret_cast<uint4*>(dst + c0) = *reinterpret_cast<uint4*>(v);
        return;
    }
    idx -= GATHER_N;
    if (idx < ACCZ_N) {
        float4 z4 = {0.f, 0.f, 0.f, 0.f};
        reinterpret_cast<float4*>(accb)[idx] = z4;
    }
}

// ---------------- conv as one flattened GEMM: BK=32, LDS-staged, double-buffered, 4 blocks/CU ----------------
// BK=32 (round 16: conv 74.5 -> <48us; occupancy doubled). Linear LDS (64B rows are
// conflict-free for this read pattern). WRITE 50.6MB is all logical output (no spill).
__global__ __launch_bounds__(256, 4) void conv_mfma(const ushort* __restrict__ xpk,
                                                    const float* __restrict__ dmask,
                                                    const float* __restrict__ qmask,
                                                    const ushort* __restrict__ wp,
                                                    const float* __restrict__ b1,
                                                    const float* __restrict__ b2,
                                                    const float* __restrict__ b3,
                                                    ushort* __restrict__ dh,
                                                    ushort* __restrict__ dlo,
                                                    ushort* __restrict__ qh,
                                                    ushort* __restrict__ qlo) {
    __shared__ __align__(16) char smem[2][16512];    // per buffer: A 130x32 (8320B) + B 128x32 (8192B)

    const int tid = threadIdx.x;
    const int bid = blockIdx.x;
    // XCD-bijective swizzle: 792 = 8 * 99
    const int swz = (bid & 7) * (CONV_BLOCKS / 8) + (bid >> 3);
    const int z = swz % 3;
    const int tile = swz / 3;
    const int l0 = tile * 128;

    const int Kdim = EMBP * (z + 1);
    const int nk = 10 * (z + 1);                // K-steps of 32
    const ushort* wpk = wp + WPOFF_C[z];
    const float* bias = (z == 0) ? b1 : ((z == 1) ? b2 : b3);

    const int wave = tid >> 6;
    const int lane = tid & 63;
    const int l15 = lane & 15;
    const int quad = lane >> 4;
    const int wm = wave >> 1;
    const int wn = wave & 1;

    // staging map: lane -> (row = round*64 + wave*16 + lane/4, col = (lane&3)*8); linear LDS dest
    const int srow = lane >> 2;
    const int scol = (lane & 3) * 8;
    const ushort* a0 = xpk + (size_t)(l0 + wave * 16 + srow) * EMBP + scol;
    const ushort* at = xpk + (size_t)(l0 + 128 + srow) * EMBP + scol;   // tail rows 128..129 (lanes 0..7)
    const ushort* b0 = wpk + (size_t)(wave * 16 + srow) * Kdim + scol;

    auto stage = [&](int buf, int kk) {
        int jj = kk / 10;                       // tap index
        int coff = (kk - jj * 10) * 32;         // A col within the 320-wide token row
        int koff = kk * 32;                     // B col within Kdim
        char* abuf = smem[buf];
        char* bbuf = smem[buf] + 8320;
#pragma unroll
        for (int p = 0; p < 2; ++p)
            gl_lds16(a0 + p * (64 * EMBP) + coff, abuf + p * 4096 + wave * 1024);
        if (wave == 0 && lane < 8)
            gl_lds16(at + coff, abuf + 8192);
#pragma unroll
        for (int p = 0; p < 2; ++p)
            gl_lds16(b0 + (size_t)p * 64 * Kdim + koff, bbuf + p * 4096 + wave * 1024);
    };

    floatx4 acc[4][4];
#pragma unroll
    for (int i = 0; i < 4; ++i)
#pragma unroll
        for (int j = 0; j < 4; ++j) acc[i][j] = (floatx4)0.f;

    stage(0, 0);
    __syncthreads();

    int jjc = 0, ccc = 0;
    int buf = 0;
    for (int kk = 0; kk < nk; ++kk) {
        if (kk + 1 < nk) stage(buf ^ 1, kk + 1);
        const char* Ab = smem[buf];
        const char* Bb = smem[buf] + 8320;
        short8 af[4], bf[4];
#pragma unroll
        for (int i = 0; i < 4; ++i) {
            int ra = wm * 64 + i * 16 + l15 + jjc;
            int rb = wn * 64 + i * 16 + l15;
            af[i] = *reinterpret_cast<const short8*>(Ab + ra * 64 + quad * 16);
            bf[i] = *reinterpret_cast<const short8*>(Bb + rb * 64 + quad * 16);
        }
#pragma unroll
        for (int i = 0; i < 4; ++i)
#pragma unroll
            for (int j = 0; j < 4; ++j)
                acc[i][j] = __builtin_amdgcn_mfma_f32_16x16x32_bf16(af[i], bf[j], acc[i][j], 0, 0, 0);
        ++ccc;
        if (ccc == 10) { ccc = 0; ++jjc; }
        __syncthreads();
        buf ^= 1;
    }

    // ---- epilogue: bias + relu + row L2-norm + mask; emit bf16 hi/lo planes ----
    float (*rowsum)[128] = reinterpret_cast<float(*)[128]>(smem);
    float bv[4];
#pragma unroll
    for (int j = 0; j < 4; ++j) bv[j] = bias[wn * 64 + j * 16 + l15];
#pragma unroll
    for (int i = 0; i < 4; ++i)
#pragma unroll
        for (int r = 0; r < 4; ++r) {
            float p = 0.f;
#pragma unroll
            for (int j = 0; j < 4; ++j) {
                float y = fmaxf(acc[i][j][r] + bv[j], 0.f);
                acc[i][j][r] = y;
                p += y * y;
            }
#pragma unroll
            for (int m = 1; m < 16; m <<= 1) p += __shfl_xor(p, m, 64);
            if (l15 == 0) rowsum[wn][wm * 64 + i * 16 + quad * 4 + r] = p;
        }
    __syncthreads();

#pragma unroll
    for (int i = 0; i < 4; ++i) {
#pragma unroll
        for (int rr = 0; rr < 4; ++rr) {
            int rl = wm * 64 + i * 16 + quad * 4 + rr;
            int r = l0 + rl;                    // global combined row
            float tot = rowsum[0][rl] + rowsum[1][rl];
            float mv;
            ushort* hp;
            ushort* lp;
            if (r < NB * DL) {
                int l = r & (DL - 1);
                if (l >= DL - z) continue;
                mv = dmask[r];
                size_t base = (size_t)z * DPLANE + (size_t)r * OD;
                hp = dh + base; lp = dlo + base;
            } else {
                int t = r - NB * DL;
                int l = t & (QL - 1);
                if (l >= QL - z) continue;
                mv = qmask[t];
                size_t base = (size_t)z * QPLANE + (size_t)t * OD;
                hp = qh + base; lp = qlo + base;
            }
            float sc = mv / (sqrtf(tot) + 1e-13f);
            int cb = wn * 64 + l15;
#pragma unroll
            for (int j = 0; j < 4; ++j) {
                float v = acc[i][j][rr] * sc;
                __hip_bfloat16 h = __float2bfloat16(v);
                float hf = __bfloat162float(h);
                hp[cb + j * 16] = *reinterpret_cast<ushort*>(&h);
                __hip_bfloat16 l = __float2bfloat16(v - hf);
                lp[cb + j * 16] = *reinterpret_cast<ushort*>(&l);
            }
        }
    }
}

// ---------------- matcher: round-16 MFMA phase + PACKED-FP32 gaussian recurrence ----------------
// grid: (vtile=8, b=32, pp=9), block 256 = 4 waves, qi-fast pp decode.
// Round 17: depth-1 load pipeline was a NULL (VGPR unchanged 52 -> compiler already
// pipelines); reverted. New lever: the gaussian's ~1100 scalar VALU/thread is ~half the
// kernel (VALUBusy 45%). gfx950 has v_pk_mul_f32/v_pk_fma_f32: the 20-bin recurrence now
// runs on float2 pairs ((x,y),(z,w)) via __builtin_elementwise_fma -> 6 packed ops per
// bin-step vs 12 scalar. Per-element math bit-identical (IEEE per-lane); only the final
// pair-sum association changes (tolerance slack is enormous).
// Bins 1..20 as 20 NAMED float2 regs (+20 VGPR, under the 128 budget of (256,4) -- the
// unique non-spilling point, proven rounds 4/5/14). Falsifiers: VGPR stuck at 52 =
// scalarized (neutral); WRITE>10MB = spill (revert).
__global__ __launch_bounds__(256, 4) void matcher_kernel(const ushort* __restrict__ qh_g,
                                                         const ushort* __restrict__ ql_g,
                                                         const ushort* __restrict__ vh_g,
                                                         const ushort* __restrict__ vl_g,
                                                         float* __restrict__ accb) {
    __shared__ __align__(16) float Sm[32 * 132];     // 16.9 KB S tile
    __shared__ float stageb[672];                    // 2.7 KB coalesced-commit staging

    const int tid = threadIdx.x;
    const int pp = blockIdx.z;
    const int b = blockIdx.y;
    const int v0 = blockIdx.x * 128;
    const int di = pp / 3;                // di SLOW
    const int qi = pp - di * 3;           // qi FAST: V-sharing blocks 256 apart
    const int Vk = 1024 - di;

    const ushort* qhb = qh_g + (size_t)qi * QPLANE + (size_t)b * (QL * OD);
    const ushort* qlb = ql_g + (size_t)qi * QPLANE + (size_t)b * (QL * OD);
    const ushort* vhb = vh_g + (size_t)di * DPLANE + (size_t)b * (DL * OD) + (size_t)v0 * OD;
    const ushort* vlb = vl_g + (size_t)di * DPLANE + (size_t)b * (DL * OD) + (size_t)v0 * OD;

    const int wave = tid >> 6;
    const int lane = tid & 63;
    const int l15 = lane & 15;
    const int quad = lane >> 4;

    floatx4 acc[2][2];
#pragma unroll
    for (int i = 0; i < 2; ++i)
#pragma unroll
        for (int j = 0; j < 2; ++j) acc[i][j] = (floatx4)0.f;

    // K = 128 as 4 windows of 32; lane's k-slice = quad*8 within each window.
#pragma unroll
    for (int kw = 0; kw < 4; ++kw) {
        const int ko = kw * 32 + quad * 8;
        short8 qh[2], ql[2], vh[2], vl[2];
#pragma unroll
        for (int i = 0; i < 2; ++i) {
            const int qr = i * 16 + l15;
            const int vr = wave * 32 + i * 16 + l15;
            qh[i] = *reinterpret_cast<const short8*>(qhb + qr * OD + ko);
            ql[i] = *reinterpret_cast<const short8*>(qlb + qr * OD + ko);
            vh[i] = *reinterpret_cast<const short8*>(vhb + (size_t)vr * OD + ko);
            vl[i] = *reinterpret_cast<const short8*>(vlb + (size_t)vr * OD + ko);
        }
#pragma unroll
        for (int i = 0; i < 2; ++i)
#pragma unroll
            for (int j = 0; j < 2; ++j) {
                acc[i][j] = __builtin_amdgcn_mfma_f32_16x16x32_bf16(qh[i], vh[j], acc[i][j], 0, 0, 0);
                acc[i][j] = __builtin_amdgcn_mfma_f32_16x16x32_bf16(qh[i], vl[j], acc[i][j], 0, 0, 0);
                acc[i][j] = __builtin_amdgcn_mfma_f32_16x16x32_bf16(ql[i], vh[j], acc[i][j], 0, 0, 0);
            }
    }

    // ---- S tile to LDS (stride 132 f32), poison v >= vmax with 1e4 ----
    const int vmax = min(128, Vk - v0);
#pragma unroll
    for (int i = 0; i < 2; ++i)
#pragma unroll
        for (int j = 0; j < 2; ++j)
#pragma unroll
            for (int r = 0; r < 4; ++r) {
                int q = i * 16 + quad * 4 + r;
                int v = wave * 32 + j * 16 + l15;
                float val = acc[i][j][r];
                if (v >= vmax) val = 1.0e4f;
                Sm[q * 132 + v] = val;
            }
    __syncthreads();

    // ---- gaussian phase: thread = (q = tid>>3, chunk c = tid&7 -> v in [c*16, c*16+16)) ----
    {
        const int q = tid >> 3;
        const int c = tid & 7;
        const float* srow = &Sm[q * 132 + c * 16];
        const float Am  = -72.13475204f;     // -log2e/(2*0.1^2)
        const float Am5 = -14.426950408f;    // 0.2*Am
        const float A0  = -721347.52f;       // -log2e/(2*0.001^2)
        const floatx2 C2 = {0x1.0p-126f, 0x1.0p-126f};

        float s00 = 0.f;
        floatx2 v01 = {0.f, 0.f}, v02 = {0.f, 0.f}, v03 = {0.f, 0.f}, v04 = {0.f, 0.f},
                v05 = {0.f, 0.f}, v06 = {0.f, 0.f}, v07 = {0.f, 0.f}, v08 = {0.f, 0.f},
                v09 = {0.f, 0.f}, v10 = {0.f, 0.f}, v11 = {0.f, 0.f}, v12 = {0.f, 0.f},
                v13 = {0.f, 0.f}, v14 = {0.f, 0.f}, v15 = {0.f, 0.f}, v16 = {0.f, 0.f},
                v17 = {0.f, 0.f}, v18 = {0.f, 0.f}, v19 = {0.f, 0.f}, v20 = {0.f, 0.f};

#define GACC2(B) { B = __builtin_elementwise_fma(t01, C2, B); \
                   B = __builtin_elementwise_fma(t23, C2, B); }
#define GSTEP2(B, g) { floatx2 g2 = {(g), (g)}; t01 *= R01 * g2; t23 *= R23 * g2; GACC2(B) }

#pragma unroll
        for (int jj = 0; jj < 4; ++jj) {
            float4 s4 = *reinterpret_cast<const float4*>(srow + jj * 4);
            float dx = s4.x - 0.95f, dy = s4.y - 0.95f, dz = s4.z - 0.95f, dwv = s4.w - 0.95f;
            float tx = __builtin_exp2f(__builtin_fmaf(Am * dx, dx, 126.f));  // 2^126 * term_1
            float ty = __builtin_exp2f(__builtin_fmaf(Am * dy, dy, 126.f));
            float tz = __builtin_exp2f(__builtin_fmaf(Am * dz, dz, 126.f));
            float tw = __builtin_exp2f(__builtin_fmaf(Am * dwv, dwv, 126.f));
            floatx2 t01 = {tx, ty}, t23 = {tz, tw};
            floatx2 R01 = {__builtin_exp2f(Am5 * dx), __builtin_exp2f(Am5 * dy)};
            floatx2 R23 = {__builtin_exp2f(Am5 * dz), __builtin_exp2f(Am5 * dwv)};
            GACC2(v01)
            GSTEP2(v02, 6.0653066e-01f) GSTEP2(v03, 2.2313016e-01f)
            GSTEP2(v04, 8.2084999e-02f) GSTEP2(v05, 3.0197383e-02f)
            GSTEP2(v06, 1.1108997e-02f) GSTEP2(v07, 4.0867714e-03f)
            GSTEP2(v08, 1.5034391e-03f) GSTEP2(v09, 5.5308438e-04f)
            GSTEP2(v10, 2.0346837e-04f) GSTEP2(v11, 7.4851830e-05f)
            GSTEP2(v12, 2.7536450e-05f) GSTEP2(v13, 1.0130095e-05f)
            GSTEP2(v14, 3.7266532e-06f) GSTEP2(v15, 1.3709590e-06f)
            GSTEP2(v16, 5.0434766e-07f) GSTEP2(v17, 1.8553914e-07f)
            GSTEP2(v18, 6.8256033e-08f) GSTEP2(v19, 2.5110699e-08f)
            GSTEP2(v20, 9.2374496e-09f)
            float ex = s4.x - 1.f, ey = s4.y - 1.f, ez = s4.z - 1.f, ew = s4.w - 1.f;
            s00 += __builtin_exp2f((A0 * ex) * ex);
            s00 += __builtin_exp2f((A0 * ey) * ey);
            s00 += __builtin_exp2f((A0 * ez) * ez);
            s00 += __builtin_exp2f((A0 * ew) * ew);
        }
#undef GSTEP2
#undef GACC2

        // pair-sum, reduce over the 8 v-chunks (lane bits 0..2); c==0 stages to LDS
#define GRED2(B, t) { float sv = B.x + B.y; \
                      sv += __shfl_xor(sv, 1, 64); sv += __shfl_xor(sv, 2, 64); \
                      sv += __shfl_xor(sv, 4, 64); \
                      if (c == 0) stageb[q * KNUM + (t)] = sv; }
        {
            float sv = s00;
            sv += __shfl_xor(sv, 1, 64); sv += __shfl_xor(sv, 2, 64); sv += __shfl_xor(sv, 4, 64);
            if (c == 0) stageb[q * KNUM + 0] = sv;
        }
        GRED2(v01, 1)  GRED2(v02, 2)  GRED2(v03, 3)  GRED2(v04, 4)  GRED2(v05, 5)
        GRED2(v06, 6)  GRED2(v07, 7)  GRED2(v08, 8)  GRED2(v09, 9)  GRED2(v10, 10)
        GRED2(v11, 11) GRED2(v12, 12) GRED2(v13, 13) GRED2(v14, 14) GRED2(v15, 15)
        GRED2(v16, 16) GRED2(v17, 17) GRED2(v18, 18) GRED2(v19, 19) GRED2(v20, 20)
#undef GRED2
    }
    __syncthreads();

    // ---- coalesced atomic commit: 672 contiguous floats; logical pair id = qi*3+di ----
    {
        float* dst = &accb[((size_t)((qi * 3 + di) * NB + b) * QL) * KNUM];
        for (int i = tid; i < 32 * KNUM; i += 256)
            atomicAdd(dst + i, stageb[i]);
    }
}

// ---------------- finalize ----------------
__global__ void finalize_kernel(const float* __restrict__ accb,
                                const float* __restrict__ qmask,
                                const float* __restrict__ dw,
                                const float* __restrict__ db,
                                float* __restrict__ out) {
    __shared__ float prod[192];
    int b = blockIdx.x;
    int tid = threadIdx.x;
    if (tid < 189) {
        int pq = tid / 21;
        int t = tid - pq * 21;
        int qi = pq / 3;
        int Qk = 32 - qi;
        const float* ab = accb + ((pq * NB + b) * QL) * KNUM + t;
        float s = 0.f;
        for (int q = 0; q < Qk; ++q)
            s += logf(fmaxf(ab[q * KNUM], 1e-10f)) * qmask[b * QL + q];
        float lg = s * 0.01f;
        out[NB + b * 189 + tid] = lg;
        prod[tid] = lg * dw[tid];
    }
    __syncthreads();
    if (tid == 0) {
        float sc = db[0];
        for (int i = 0; i < 189; ++i) sc += prod[i];
        out[b] = sc;
    }
}

// ---------------- launcher ----------------
extern "C" void kernel_launch(void* const* d_in, const int* in_sizes, int n_in,
                              void* d_out, int out_size, void* d_ws, size_t ws_size,
                              hipStream_t stream) {
    const int* qids = (const int*)d_in[0];
    const float* qmask = (const float*)d_in[1];
    const int* dids = (const int*)d_in[2];
    const float* dmask = (const float*)d_in[3];
    const float* emb = (const float*)d_in[4];
    const float* w1 = (const float*)d_in[5];
    const float* b1 = (const float*)d_in[6];
    const float* w2 = (const float*)d_in[7];
    const float* b2 = (const float*)d_in[8];
    const float* w3 = (const float*)d_in[9];
    const float* b3 = (const float*)d_in[10];
    const float* dw = (const float*)d_in[11];
    const float* db = (const float*)d_in[12];
    float* out = (float*)d_out;
    float* ws = (float*)d_ws;

    ushort* wp  = (ushort*)(ws + WP_OFF);
    ushort* dpk = (ushort*)(ws + DPK_OFF);
    ushort* qpk = (ushort*)(ws + QPK_OFF);
    ushort* qh  = (ushort*)(ws + QH_OFF);
    ushort* qlo = (ushort*)(ws + QLO_OFF);
    ushort* dh  = (ushort*)(ws + DH_OFF);
    ushort* dlo = (ushort*)(ws + DLO_OFF);
    float* accb = ws + ACC_OFF;

    gather_prep<<<(PREPW_N + GATHER_N + ACCZ_N + 255) / 256, 256, 0, stream>>>(
        emb, dids, qids, w1, w2, w3, dpk, qpk, wp, accb);

    conv_mfma<<<CONV_BLOCKS, 256, 0, stream>>>(dpk, dmask, qmask, wp, b1, b2, b3, dh, dlo, qh, qlo);

    matcher_kernel<<<dim3(8, NB, 9), 256, 0, stream>>>(qh, qlo, dh, dlo, accb);
    finalize_kernel<<<NB, 256, 0, stream>>>(accb, qmask, dw, db, out);
}